// Round 1
// baseline (103.666 us; speedup 1.0000x reference)
//
#include <hip/hip_runtime.h>
#include <math.h>

#define T_DIM   2048
#define ROW_IN  28     // M*K*C = 2*7*2
#define ROW_OUT 181    // 28 + 91 + 28 + 28 + 6
#define EPSF    1e-6f

// triu_indices(14, k=1) pair tables, row-major order: (0,1),(0,2),...,(12,13)
__constant__ unsigned char d_iu[91] = {
    0,0,0,0,0,0,0,0,0,0,0,0,0,
    1,1,1,1,1,1,1,1,1,1,1,1,
    2,2,2,2,2,2,2,2,2,2,2,
    3,3,3,3,3,3,3,3,3,3,
    4,4,4,4,4,4,4,4,4,
    5,5,5,5,5,5,5,5,
    6,6,6,6,6,6,6,
    7,7,7,7,7,7,
    8,8,8,8,8,
    9,9,9,9,
    10,10,10,
    11,11,
    12
};
__constant__ unsigned char d_ju[91] = {
    1,2,3,4,5,6,7,8,9,10,11,12,13,
    2,3,4,5,6,7,8,9,10,11,12,13,
    3,4,5,6,7,8,9,10,11,12,13,
    4,5,6,7,8,9,10,11,12,13,
    5,6,7,8,9,10,11,12,13,
    6,7,8,9,10,11,12,13,
    7,8,9,10,11,12,13,
    8,9,10,11,12,13,
    9,10,11,12,13,
    10,11,12,13,
    11,12,13,
    12,13,
    13
};

__global__ __launch_bounds__(256)
void feat_kernel(const float* __restrict__ x, float* __restrict__ out, int total)
{
    int j = blockIdx.x * blockDim.x + threadIdx.x;
    if (j >= total) return;

    int g = j / ROW_OUT;            // g = b*T + t
    int c = j - g * ROW_OUT;        // column within the 181-wide output row
    int t = g & (T_DIM - 1);        // T is a power of two

    const float* __restrict__ row = x + (size_t)g * ROW_IN;

    float val;
    if (c < 28) {
        // raw x copy
        val = row[c];
    } else if (c < 119) {
        // pairwise distances between the 14 (x,y) points
        int p = c - 28;
        int i  = d_iu[p];
        int jj = d_ju[p];
        float dx = row[2*i]   - row[2*jj];
        float dy = row[2*i+1] - row[2*jj+1];
        val = sqrtf(dx*dx + dy*dy);
    } else if (c < 147) {
        // velocity: x[t] - x[t-1], zero at t==0
        int e = c - 119;
        val = (t > 0) ? (row[e] - row[e - ROW_IN]) : 0.0f;
    } else if (c < 175) {
        // acceleration: v[t] - v[t-1]
        int e = c - 147;
        if (t >= 2)      val = row[e] - 2.0f*row[e - ROW_IN] + row[e - 2*ROW_IN];
        else if (t == 1) val = row[e] - row[e - ROW_IN];   // a[1] = v[1] - 0
        else             val = 0.0f;
    } else {
        // body features: per mouse m: [length, blc, curvature]
        int idx = c - 175;
        int m = idx / 3;
        int q = idx - 3*m;
        const float* pr = row + m*14;           // point p = m*7+k, float off = p*2
        float nx = pr[0],  ny = pr[1];          // nose  (k=0)
        float kx = pr[6],  ky = pr[7];          // neck  (k=3)
        float tx = pr[12], ty = pr[13];         // tail  (k=6)
        if (q == 0) {
            float dx = nx - tx, dy = ny - ty;
            val = sqrtf(dx*dx + dy*dy);
        } else if (q == 1) {
            if (m == 0) {
                val = 0.0f;                     // blc[m=0] is zero
            } else {
                float d1x = row[14] - row[26], d1y = row[15] - row[27];
                float d0x = row[0]  - row[12], d0y = row[1]  - row[13];
                val = sqrtf(d1x*d1x + d1y*d1y) - sqrtf(d0x*d0x + d0y*d0y);
            }
        } else {
            float v1x = nx - kx, v1y = ny - ky;
            float v2x = tx - kx, v2y = ty - ky;
            float n1 = sqrtf(v1x*v1x + v1y*v1y) + EPSF;
            float n2 = sqrtf(v2x*v2x + v2y*v2y) + EPSF;
            float cosang = (v1x*v2x + v1y*v2y) / (n1 * n2);
            cosang = fminf(fmaxf(cosang, -1.0f + EPSF), 1.0f - EPSF);
            val = acosf(cosang);
        }
    }
    out[j] = val;
}

extern "C" void kernel_launch(void* const* d_in, const int* in_sizes, int n_in,
                              void* d_out, int out_size, void* d_ws, size_t ws_size,
                              hipStream_t stream)
{
    const float* x = (const float*)d_in[0];
    float* out = (float*)d_out;
    int total = out_size;           // 64*2048*181
    int block = 256;
    int grid = (total + block - 1) / block;
    feat_kernel<<<grid, block, 0, stream>>>(x, out, total);
}

// Round 2
// 66.916 us; speedup vs baseline: 1.5492x; 1.5492x over previous
//
#include <hip/hip_runtime.h>
#include <math.h>

#define T_DIM    2048
#define ROW_IN   28     // M*K*C = 2*7*2
#define ROW_OUT  181    // 28 + 91 + 28 + 28 + 6
#define EPSF     1e-6f
#define R_PER_BLK 64
#define LDS_ROWS (R_PER_BLK + 2)             // +2 history rows for v/a
#define OUT_PER_BLK (R_PER_BLK * ROW_OUT)    // 11584
#define STAGE_F4 (LDS_ROWS * ROW_IN / 4)     // 462 float4 per block

// triu_indices(14, k=1) pair tables, row-major order: (0,1),(0,2),...,(12,13)
__constant__ unsigned char d_iu[91] = {
    0,0,0,0,0,0,0,0,0,0,0,0,0,
    1,1,1,1,1,1,1,1,1,1,1,1,
    2,2,2,2,2,2,2,2,2,2,2,
    3,3,3,3,3,3,3,3,3,3,
    4,4,4,4,4,4,4,4,4,
    5,5,5,5,5,5,5,5,
    6,6,6,6,6,6,6,
    7,7,7,7,7,7,
    8,8,8,8,8,
    9,9,9,9,
    10,10,10,
    11,11,
    12
};
__constant__ unsigned char d_ju[91] = {
    1,2,3,4,5,6,7,8,9,10,11,12,13,
    2,3,4,5,6,7,8,9,10,11,12,13,
    3,4,5,6,7,8,9,10,11,12,13,
    4,5,6,7,8,9,10,11,12,13,
    5,6,7,8,9,10,11,12,13,
    6,7,8,9,10,11,12,13,
    7,8,9,10,11,12,13,
    8,9,10,11,12,13,
    9,10,11,12,13,
    10,11,12,13,
    11,12,13,
    12,13,
    13
};

__global__ __launch_bounds__(256)
void feat_kernel(const float* __restrict__ x, float* __restrict__ out)
{
    __shared__ float lds[LDS_ROWS * ROW_IN];   // 7392 B

    const int g0 = blockIdx.x * R_PER_BLK;

    // Cooperative float4 staging of rows [g0-2, g0+R_PER_BLK).
    // Global float index base (g0-2)*28 is divisible by 4 -> aligned float4.
    {
        const float4* __restrict__ src4 = (const float4*)x;
        float4* lds4 = (float4*)lds;
        const int first4 = (g0 - 2) * (ROW_IN / 4);   // (g0-2)*7, negative only for block 0
        for (int i = threadIdx.x; i < STAGE_F4; i += 256) {
            int s = first4 + i;
            float4 v;
            if (s >= 0) v = src4[s];
            else        v = make_float4(0.f, 0.f, 0.f, 0.f);   // unused (t==0/1 special-cased)
            lds4[i] = v;
        }
    }
    __syncthreads();

    const size_t out_base = (size_t)g0 * ROW_OUT;

    for (int j = threadIdx.x; j < OUT_PER_BLK; j += 256) {
        int r = j / ROW_OUT;                  // row within block (magic-mul)
        int c = j - r * ROW_OUT;              // output column [0,181)
        int t = (g0 + r) & (T_DIM - 1);       // time index within batch

        const float* __restrict__ row = &lds[(r + 2) * ROW_IN];

        float val;
        if (c < 28) {
            val = row[c];
        } else if (c < 119) {
            // pairwise distances between the 14 (x,y) points
            int p  = c - 28;
            int i  = d_iu[p];
            int jj = d_ju[p];
            float dx = row[2*i]   - row[2*jj];
            float dy = row[2*i+1] - row[2*jj+1];
            val = sqrtf(dx*dx + dy*dy);
        } else if (c < 147) {
            // velocity: x[t] - x[t-1], zero at t==0
            int e = c - 119;
            val = (t > 0) ? (row[e] - row[e - ROW_IN]) : 0.0f;
        } else if (c < 175) {
            // acceleration: v[t] - v[t-1]
            int e = c - 147;
            if (t >= 2)      val = row[e] - 2.0f*row[e - ROW_IN] + row[e - 2*ROW_IN];
            else if (t == 1) val = row[e] - row[e - ROW_IN];   // a[1] = v[1] - 0
            else             val = 0.0f;
        } else {
            // body features per mouse m: [length, blc, curvature]
            int idx = c - 175;
            int m = idx / 3;
            int q = idx - 3*m;
            const float* pr = row + m*14;
            float nx = pr[0],  ny = pr[1];     // nose (k=0)
            float kx = pr[6],  ky = pr[7];     // neck (k=3)
            float tx = pr[12], ty = pr[13];    // tail (k=6)
            if (q == 0) {
                float dx = nx - tx, dy = ny - ty;
                val = sqrtf(dx*dx + dy*dy);
            } else if (q == 1) {
                if (m == 0) {
                    val = 0.0f;
                } else {
                    float d1x = row[14] - row[26], d1y = row[15] - row[27];
                    float d0x = row[0]  - row[12], d0y = row[1]  - row[13];
                    val = sqrtf(d1x*d1x + d1y*d1y) - sqrtf(d0x*d0x + d0y*d0y);
                }
            } else {
                float v1x = nx - kx, v1y = ny - ky;
                float v2x = tx - kx, v2y = ty - ky;
                float n1 = sqrtf(v1x*v1x + v1y*v1y) + EPSF;
                float n2 = sqrtf(v2x*v2x + v2y*v2y) + EPSF;
                float cosang = (v1x*v2x + v1y*v2y) / (n1 * n2);
                cosang = fminf(fmaxf(cosang, -1.0f + EPSF), 1.0f - EPSF);
                val = acosf(cosang);
            }
        }
        out[out_base + j] = val;
    }
}

extern "C" void kernel_launch(void* const* d_in, const int* in_sizes, int n_in,
                              void* d_out, int out_size, void* d_ws, size_t ws_size,
                              hipStream_t stream)
{
    const float* x = (const float*)d_in[0];
    float* out = (float*)d_out;
    int n_rows = in_sizes[0] / ROW_IN;        // 131072
    int grid = n_rows / R_PER_BLK;            // 2048 blocks
    feat_kernel<<<grid, 256, 0, stream>>>(x, out);
}

// Round 3
// 28.641 us; speedup vs baseline: 3.6195x; 2.3364x over previous
//
#include <hip/hip_runtime.h>
#include <math.h>

#define T_DIM    2048
#define ROW_IN   28          // M*K*C = 2*7*2
#define ROW_OUT  181         // 28 + 91 + 28 + 28 + 6
#define EPSF     1e-6f
#define R_BLK    32          // rows per block
#define IN_STRIDE 30         // padded LDS row stride (floats): odd f2-stride -> conflict-free
#define OUT_FLOATS (R_BLK * ROW_OUT)       // 5792
#define OUT_F4     (OUT_FLOATS / 4)        // 1448
#define STAGE_F4   (R_BLK * (ROW_IN/4))    // 224
#define CVA_ITEMS  (R_BLK * (ROW_IN/4))    // 224  (7 f4-cols x 32 rows)
#define DIST_ITEMS (R_BLK * 91)            // 2912
#define BODY_ITEMS (R_BLK * 6)             // 192

// packed (i | j<<8) for triu_indices(14, k=1), row-major
__constant__ unsigned short d_pair[91] = {
    0x0100,0x0200,0x0300,0x0400,0x0500,0x0600,0x0700,0x0800,0x0900,0x0A00,0x0B00,0x0C00,0x0D00,
    0x0201,0x0301,0x0401,0x0501,0x0601,0x0701,0x0801,0x0901,0x0A01,0x0B01,0x0C01,0x0D01,
    0x0302,0x0402,0x0502,0x0602,0x0702,0x0802,0x0902,0x0A02,0x0B02,0x0C02,0x0D02,
    0x0403,0x0503,0x0603,0x0703,0x0803,0x0903,0x0A03,0x0B03,0x0C03,0x0D03,
    0x0504,0x0604,0x0704,0x0804,0x0904,0x0A04,0x0B04,0x0C04,0x0D04,
    0x0605,0x0705,0x0805,0x0905,0x0A05,0x0B05,0x0C05,0x0D05,
    0x0706,0x0806,0x0906,0x0A06,0x0B06,0x0C06,0x0D06,
    0x0807,0x0907,0x0A07,0x0B07,0x0C07,0x0D07,
    0x0908,0x0A08,0x0B08,0x0C08,0x0D08,
    0x0A09,0x0B09,0x0C09,0x0D09,
    0x0B0A,0x0C0A,0x0D0A,
    0x0C0B,0x0D0B,
    0x0D0C
};

__global__ __launch_bounds__(256)
void feat_kernel(const float* __restrict__ x, float* __restrict__ out)
{
    __shared__ float in_lds[R_BLK * IN_STRIDE];    // 3840 B
    __shared__ float out_lds[OUT_FLOATS];          // 23168 B, exact global tile layout

    const int tid = threadIdx.x;
    const int g0  = blockIdx.x * R_BLK;
    const float4* __restrict__ x4 = (const float4*)x;

    // ---- Phase 0: stage 32 current rows into in_lds (padded stride) ----
    // 224 f4 items, contiguous global reads.
    if (tid < STAGE_F4) {
        float4 v = x4[g0 * (ROW_IN/4) + tid];
        int r = tid / 7;            // magic-mul
        int k = tid - 7 * r;
        float* dst = &in_lds[r * IN_STRIDE + 4 * k];
        // 8B-aligned (even offsets) -> two b64 writes
        ((float2*)dst)[0] = make_float2(v.x, v.y);
        ((float2*)dst)[1] = make_float2(v.z, v.w);
    }

    // ---- Phase 1: copy + velocity + acceleration (reads global f4, L1-hot) ----
    if (tid < CVA_ITEMS) {
        int r = tid & (R_BLK - 1);
        int k = tid >> 5;                       // f4 column 0..6
        int g = g0 + r;
        int t = g & (T_DIM - 1);
        int gm1 = (t >= 1) ? g - 1 : g;         // safe indices
        int gm2 = (t >= 2) ? g - 2 : g;
        float4 c4 = x4[(size_t)g  * 7 + k];
        float4 p4 = x4[(size_t)gm1 * 7 + k];
        float4 q4 = x4[(size_t)gm2 * 7 + k];

        float vx[4], va[4], vc[4];
        float c[4] = {c4.x, c4.y, c4.z, c4.w};
        float p[4] = {p4.x, p4.y, p4.z, p4.w};
        float q[4] = {q4.x, q4.y, q4.z, q4.w};
        #pragma unroll
        for (int e = 0; e < 4; ++e) {
            vc[e] = c[e];
            float v1 = c[e] - p[e];
            vx[e] = (t >= 1) ? v1 : 0.0f;
            float a2 = c[e] - 2.0f * p[e] + q[e];
            va[e] = (t >= 2) ? a2 : ((t == 1) ? v1 : 0.0f);
        }
        float* orow = &out_lds[r * ROW_OUT];
        int cb = 4 * k;
        #pragma unroll
        for (int e = 0; e < 4; ++e) {
            orow[cb + e]       = vc[e];     // raw copy  [0,28)
            orow[119 + cb + e] = vx[e];     // velocity  [119,147)
            orow[147 + cb + e] = va[e];     // accel     [147,175)
        }
    }

    __syncthreads();   // in_lds ready for phases 2-3

    // ---- Phase 2: pairwise distances (uniform path, f2 LDS reads) ----
    {
        const float2* __restrict__ in2 = (const float2*)in_lds;   // stride 15 f2 per row
        for (int w = tid; w < DIST_ITEMS; w += 256) {
            int r = w & (R_BLK - 1);
            int p = w >> 5;                    // 0..90
            unsigned pr = d_pair[p];
            int i  = pr & 0xFF;
            int jj = pr >> 8;
            int rb = r * (IN_STRIDE / 2);
            float2 a = in2[rb + i];
            float2 b = in2[rb + jj];
            float dx = a.x - b.x;
            float dy = a.y - b.y;
            out_lds[r * ROW_OUT + 28 + p] = sqrtf(dx * dx + dy * dy);
        }
    }

    // ---- Phase 3: body features [175,181): per (r, idx) ----
    if (tid < BODY_ITEMS) {
        int r   = tid & (R_BLK - 1);
        int idx = tid >> 5;                    // 0..5
        int m   = idx >= 3 ? 1 : 0;
        int q   = idx - 3 * m;
        const float* row = &in_lds[r * IN_STRIDE];
        const float* pr  = row + m * 14;
        float val;
        if (q == 0) {
            float dx = pr[0] - pr[12], dy = pr[1] - pr[13];
            val = sqrtf(dx * dx + dy * dy);
        } else if (q == 1) {
            if (m == 0) val = 0.0f;
            else {
                float d1x = row[14] - row[26], d1y = row[15] - row[27];
                float d0x = row[0]  - row[12], d0y = row[1]  - row[13];
                val = sqrtf(d1x*d1x + d1y*d1y) - sqrtf(d0x*d0x + d0y*d0y);
            }
        } else {
            float v1x = pr[0]  - pr[6], v1y = pr[1]  - pr[7];
            float v2x = pr[12] - pr[6], v2y = pr[13] - pr[7];
            float n1 = sqrtf(v1x*v1x + v1y*v1y) + EPSF;
            float n2 = sqrtf(v2x*v2x + v2y*v2y) + EPSF;
            float cosang = (v1x*v2x + v1y*v2y) / (n1 * n2);
            cosang = fminf(fmaxf(cosang, -1.0f + EPSF), 1.0f - EPSF);
            val = acosf(cosang);
        }
        out_lds[r * ROW_OUT + 175 + idx] = val;
    }

    __syncthreads();   // out tile complete

    // ---- Phase 4: coalesced f4 store of the whole tile ----
    {
        const float4* __restrict__ o4 = (const float4*)out_lds;
        float4* __restrict__ g4 = (float4*)out + (size_t)blockIdx.x * OUT_F4;
        #pragma unroll 2
        for (int w = tid; w < OUT_F4; w += 256) {
            g4[w] = o4[w];
        }
    }
}

extern "C" void kernel_launch(void* const* d_in, const int* in_sizes, int n_in,
                              void* d_out, int out_size, void* d_ws, size_t ws_size,
                              hipStream_t stream)
{
    const float* x = (const float*)d_in[0];
    float* out = (float*)d_out;
    int n_rows = in_sizes[0] / ROW_IN;     // 131072
    int grid = n_rows / R_BLK;             // 4096 blocks
    feat_kernel<<<grid, 256, 0, stream>>>(x, out);
}

// Round 5
// 23.108 us; speedup vs baseline: 4.4861x; 1.2394x over previous
//
#include <hip/hip_runtime.h>
#include <math.h>

#define T_DIM    2048
#define ROW_IN   28          // M*K*C = 2*7*2
#define ROW_OUT  181         // 28 + 91 + 28 + 28 + 6
#define EPSF     1e-6f
#define R_BLK    16          // rows per block
#define IN_STRIDE 30         // padded LDS row stride (floats)
#define OUT_FLOATS (R_BLK * ROW_OUT)       // 2896
#define OUT_F4     (OUT_FLOATS / 4)        // 724
#define CVA_ITEMS  (R_BLK * (ROW_IN/4))    // 112  (7 f4-cols x 16 rows)
#define DIST_ITEMS (R_BLK * 91)            // 1456
#define BODY_ITEMS (R_BLK * 6)             // 96

typedef float vf4 __attribute__((ext_vector_type(4)));   // native vector for NT stores

// packed (i | j<<8) for triu_indices(14, k=1), row-major
__constant__ unsigned short d_pair[91] = {
    0x0100,0x0200,0x0300,0x0400,0x0500,0x0600,0x0700,0x0800,0x0900,0x0A00,0x0B00,0x0C00,0x0D00,
    0x0201,0x0301,0x0401,0x0501,0x0601,0x0701,0x0801,0x0901,0x0A01,0x0B01,0x0C01,0x0D01,
    0x0302,0x0402,0x0502,0x0602,0x0702,0x0802,0x0902,0x0A02,0x0B02,0x0C02,0x0D02,
    0x0403,0x0503,0x0603,0x0703,0x0803,0x0903,0x0A03,0x0B03,0x0C03,0x0D03,
    0x0504,0x0604,0x0704,0x0804,0x0904,0x0A04,0x0B04,0x0C04,0x0D04,
    0x0605,0x0705,0x0805,0x0905,0x0A05,0x0B05,0x0C05,0x0D05,
    0x0706,0x0806,0x0906,0x0A06,0x0B06,0x0C06,0x0D06,
    0x0807,0x0907,0x0A07,0x0B07,0x0C07,0x0D07,
    0x0908,0x0A08,0x0B08,0x0C08,0x0D08,
    0x0A09,0x0B09,0x0C09,0x0D09,
    0x0B0A,0x0C0A,0x0D0A,
    0x0C0B,0x0D0B,
    0x0D0C
};

__global__ __launch_bounds__(256)
void feat_kernel(const float* __restrict__ x, float* __restrict__ out)
{
    __shared__ float in_lds[R_BLK * IN_STRIDE];    // 1920 B
    __shared__ float out_lds[OUT_FLOATS];          // 11584 B, exact global tile layout

    const int tid = threadIdx.x;
    const int g0  = blockIdx.x * R_BLK;
    const vf4* __restrict__ x4 = (const vf4*)x;
    const size_t base7 = (size_t)g0 * 7;

    // ---- Phase 0+1 (merged): stage rows into in_lds AND emit copy/v/a ----
    if (tid < CVA_ITEMS) {
        int r = tid / 7;                       // magic-mul
        int k = tid - 7 * r;                   // f4 column 0..6
        int t = (g0 + r) & (T_DIM - 1);

        vf4 c4 = x4[base7 + tid];                               // current row
        vf4 p4 = x4[base7 + ((t >= 1) ? tid - 7  : tid)];       // row t-1
        vf4 q4 = x4[base7 + ((t >= 2) ? tid - 14 : tid)];       // row t-2

        // stage current row into in_lds (even float offset -> aligned f2)
        float* dst = &in_lds[r * IN_STRIDE + 4 * k];
        ((float2*)dst)[0] = make_float2(c4.x, c4.y);
        ((float2*)dst)[1] = make_float2(c4.z, c4.w);

        float c[4] = {c4.x, c4.y, c4.z, c4.w};
        float p[4] = {p4.x, p4.y, p4.z, p4.w};
        float q[4] = {q4.x, q4.y, q4.z, q4.w};
        float* orow = &out_lds[r * ROW_OUT];
        int cb = 4 * k;
        #pragma unroll
        for (int e = 0; e < 4; ++e) {
            float v1 = c[e] - p[e];
            float a2 = c[e] - 2.0f * p[e] + q[e];
            float vv = (t >= 1) ? v1 : 0.0f;
            float aa = (t >= 2) ? a2 : ((t == 1) ? v1 : 0.0f);
            orow[cb + e]       = c[e];      // raw copy  [0,28)
            orow[119 + cb + e] = vv;        // velocity  [119,147)
            orow[147 + cb + e] = aa;        // accel     [147,175)
        }
    }

    __syncthreads();   // in_lds ready

    // ---- Phase 2: pairwise distances (uniform, f2 LDS reads) ----
    {
        const float2* __restrict__ in2 = (const float2*)in_lds;   // 15 f2 per row
        for (int w = tid; w < DIST_ITEMS; w += 256) {
            int r = w & (R_BLK - 1);
            int p = w >> 4;                    // 0..90
            unsigned pr = d_pair[p];
            int i  = pr & 0xFF;
            int jj = pr >> 8;
            int rb = r * (IN_STRIDE / 2);
            float2 a = in2[rb + i];
            float2 b = in2[rb + jj];
            float dx = a.x - b.x;
            float dy = a.y - b.y;
            out_lds[r * ROW_OUT + 28 + p] = sqrtf(dx * dx + dy * dy);
        }
    }

    // ---- Phase 3: body features [175,181) ----
    if (tid < BODY_ITEMS) {
        int r   = tid & (R_BLK - 1);
        int idx = tid >> 4;                    // 0..5
        int m   = idx >= 3 ? 1 : 0;
        int q   = idx - 3 * m;
        const float* row = &in_lds[r * IN_STRIDE];
        const float* pr  = row + m * 14;
        float val;
        if (q == 0) {
            float dx = pr[0] - pr[12], dy = pr[1] - pr[13];
            val = sqrtf(dx * dx + dy * dy);
        } else if (q == 1) {
            if (m == 0) val = 0.0f;
            else {
                float d1x = row[14] - row[26], d1y = row[15] - row[27];
                float d0x = row[0]  - row[12], d0y = row[1]  - row[13];
                val = sqrtf(d1x*d1x + d1y*d1y) - sqrtf(d0x*d0x + d0y*d0y);
            }
        } else {
            float v1x = pr[0]  - pr[6], v1y = pr[1]  - pr[7];
            float v2x = pr[12] - pr[6], v2y = pr[13] - pr[7];
            float n1 = sqrtf(v1x*v1x + v1y*v1y) + EPSF;
            float n2 = sqrtf(v2x*v2x + v2y*v2y) + EPSF;
            float cosang = (v1x*v2x + v1y*v2y) / (n1 * n2);
            cosang = fminf(fmaxf(cosang, -1.0f + EPSF), 1.0f - EPSF);
            val = acosf(cosang);
        }
        out_lds[r * ROW_OUT + 175 + idx] = val;
    }

    __syncthreads();   // out tile complete

    // ---- Phase 4: coalesced non-temporal f4 store of the whole tile ----
    {
        const vf4* __restrict__ o4 = (const vf4*)out_lds;
        vf4* __restrict__ g4 = (vf4*)out + (size_t)blockIdx.x * OUT_F4;
        #pragma unroll 3
        for (int w = tid; w < OUT_F4; w += 256) {
            __builtin_nontemporal_store(o4[w], &g4[w]);
        }
    }
}

extern "C" void kernel_launch(void* const* d_in, const int* in_sizes, int n_in,
                              void* d_out, int out_size, void* d_ws, size_t ws_size,
                              hipStream_t stream)
{
    const float* x = (const float*)d_in[0];
    float* out = (float*)d_out;
    int n_rows = in_sizes[0] / ROW_IN;     // 131072
    int grid = n_rows / R_BLK;             // 8192 blocks
    feat_kernel<<<grid, 256, 0, stream>>>(x, out);
}

// Round 6
// 21.734 us; speedup vs baseline: 4.7697x; 1.0632x over previous
//
#include <hip/hip_runtime.h>
#include <math.h>

#define T_DIM    2048
#define ROW_IN   28          // M*K*C = 2*7*2
#define ROW_OUT  181         // 28 + 91 + 28 + 28 + 6
#define EPSF     1e-6f
#define R_BLK    16          // rows per block
#define SLOTS    (R_BLK + 2)               // staged rows incl. 2 history
#define IN_STRIDE 30                        // padded LDS row stride (floats)
#define OUT_FLOATS (R_BLK * ROW_OUT)       // 2896
#define OUT_F4     (OUT_FLOATS / 4)        // 724
#define STAGE_F4   (SLOTS * 7)             // 126 f4 loads per block
#define CVA_ITEMS  (R_BLK * 7)             // 112
#define DIST_ITEMS (R_BLK * 91)            // 1456
#define BODY_ITEMS (R_BLK * 6)             // 96

typedef float vf4 __attribute__((ext_vector_type(4)));   // native vector for NT stores

// packed (i | j<<8) for triu_indices(14, k=1), row-major
__constant__ unsigned short d_pair[91] = {
    0x0100,0x0200,0x0300,0x0400,0x0500,0x0600,0x0700,0x0800,0x0900,0x0A00,0x0B00,0x0C00,0x0D00,
    0x0201,0x0301,0x0401,0x0501,0x0601,0x0701,0x0801,0x0901,0x0A01,0x0B01,0x0C01,0x0D01,
    0x0302,0x0402,0x0502,0x0602,0x0702,0x0802,0x0902,0x0A02,0x0B02,0x0C02,0x0D02,
    0x0403,0x0503,0x0603,0x0703,0x0803,0x0903,0x0A03,0x0B03,0x0C03,0x0D03,
    0x0504,0x0604,0x0704,0x0804,0x0904,0x0A04,0x0B04,0x0C04,0x0D04,
    0x0605,0x0705,0x0805,0x0905,0x0A05,0x0B05,0x0C05,0x0D05,
    0x0706,0x0806,0x0906,0x0A06,0x0B06,0x0C06,0x0D06,
    0x0807,0x0907,0x0A07,0x0B07,0x0C07,0x0D07,
    0x0908,0x0A08,0x0B08,0x0C08,0x0D08,
    0x0A09,0x0B09,0x0C09,0x0D09,
    0x0B0A,0x0C0A,0x0D0A,
    0x0C0B,0x0D0B,
    0x0D0C
};

__global__ __launch_bounds__(256)
void feat_kernel(const float* __restrict__ x, float* __restrict__ out)
{
    __shared__ float in_lds[SLOTS * IN_STRIDE];    // 2160 B (rows g0-2 .. g0+15)
    __shared__ unsigned int tbl[91];               // packed byte-offsets (i*8 | (j*8)<<16)
    __shared__ float out_lds[OUT_FLOATS];          // 11584 B, exact global tile layout

    const int tid = threadIdx.x;
    const int g0  = blockIdx.x * R_BLK;
    const vf4* __restrict__ x4 = (const vf4*)x;

    // ---- Phase 0: stage 18 input rows + pair table into LDS ----
    if (tid < STAGE_F4) {
        int sg = (g0 - 2) * 7 + tid;               // global f4 index, <0 only for block 0
        if (sg < 0) sg = 0;                        // harmless clamp (values masked later)
        vf4 v = x4[sg];
        int s = tid / 7;                           // slot 0..17
        int k = tid - 7 * s;
        float* dst = &in_lds[s * IN_STRIDE + 4 * k];
        ((float2*)dst)[0] = make_float2(v.x, v.y);
        ((float2*)dst)[1] = make_float2(v.z, v.w);
    } else if (tid >= 128 && tid < 128 + 91) {
        unsigned v = d_pair[tid - 128];
        tbl[tid - 128] = ((v & 0xFFu) * 8u) | (((v >> 8) * 8u) << 16);
    }

    __syncthreads();   // staging complete

    // ---- Phase 1: copy + velocity + acceleration (all reads from LDS) ----
    if (tid < CVA_ITEMS) {
        int r = tid / 7;                           // row 0..15
        int k = tid - 7 * r;                       // f4 column 0..6
        int t = (g0 + r) & (T_DIM - 1);
        const float* cr = &in_lds[(r + 2) * IN_STRIDE + 4 * k];
        const float* pr = &in_lds[(r + 1) * IN_STRIDE + 4 * k];
        const float* qr = &in_lds[(r    ) * IN_STRIDE + 4 * k];
        float2 ca = *(const float2*)cr,  cb2 = *(const float2*)(cr + 2);
        float2 pa = *(const float2*)pr,  pb2 = *(const float2*)(pr + 2);
        float2 qa = *(const float2*)qr,  qb2 = *(const float2*)(qr + 2);
        float c[4] = {ca.x, ca.y, cb2.x, cb2.y};
        float p[4] = {pa.x, pa.y, pb2.x, pb2.y};
        float q[4] = {qa.x, qa.y, qb2.x, qb2.y};
        float* orow = &out_lds[r * ROW_OUT];
        int cb = 4 * k;
        #pragma unroll
        for (int e = 0; e < 4; ++e) {
            float v1 = c[e] - p[e];
            float a2 = c[e] - 2.0f * p[e] + q[e];
            float vv = (t >= 1) ? v1 : 0.0f;
            float aa = (t >= 2) ? a2 : ((t == 1) ? v1 : 0.0f);
            orow[cb + e]       = c[e];      // raw copy  [0,28)
            orow[119 + cb + e] = vv;        // velocity  [119,147)
            orow[147 + cb + e] = aa;        // accel     [147,175)
        }
    }

    // ---- Phase 2: pairwise distances (LDS table + f2 LDS reads) ----
    {
        const char* ldsb = (const char*)in_lds;
        #pragma unroll
        for (int it = 0; it < 6; ++it) {
            int w = tid + it * 256;
            if (it == 5 && w >= DIST_ITEMS) break;
            int r = w & (R_BLK - 1);
            int p = w >> 4;                        // 0..90
            unsigned off = tbl[p];
            int rb = (r + 2) * (IN_STRIDE * 4);    // row base in bytes
            float2 a = *(const float2*)(ldsb + rb + (off & 0xFFFFu));
            float2 b = *(const float2*)(ldsb + rb + (off >> 16));
            float dx = a.x - b.x;
            float dy = a.y - b.y;
            out_lds[r * ROW_OUT + 28 + p] = sqrtf(dx * dx + dy * dy);
        }
    }

    // ---- Phase 3: body features [175,181) ----
    if (tid < BODY_ITEMS) {
        int r   = tid & (R_BLK - 1);
        int idx = tid >> 4;                        // 0..5
        int m   = idx >= 3 ? 1 : 0;
        int q   = idx - 3 * m;
        const float* row = &in_lds[(r + 2) * IN_STRIDE];
        const float* pr  = row + m * 14;
        float val;
        if (q == 0) {
            float dx = pr[0] - pr[12], dy = pr[1] - pr[13];
            val = sqrtf(dx * dx + dy * dy);
        } else if (q == 1) {
            if (m == 0) val = 0.0f;
            else {
                float d1x = row[14] - row[26], d1y = row[15] - row[27];
                float d0x = row[0]  - row[12], d0y = row[1]  - row[13];
                val = sqrtf(d1x*d1x + d1y*d1y) - sqrtf(d0x*d0x + d0y*d0y);
            }
        } else {
            float v1x = pr[0]  - pr[6], v1y = pr[1]  - pr[7];
            float v2x = pr[12] - pr[6], v2y = pr[13] - pr[7];
            float n1 = sqrtf(v1x*v1x + v1y*v1y) + EPSF;
            float n2 = sqrtf(v2x*v2x + v2y*v2y) + EPSF;
            float cosang = (v1x*v2x + v1y*v2y) / (n1 * n2);
            cosang = fminf(fmaxf(cosang, -1.0f + EPSF), 1.0f - EPSF);
            val = acosf(cosang);
        }
        out_lds[r * ROW_OUT + 175 + idx] = val;
    }

    __syncthreads();   // out tile complete

    // ---- Phase 4: coalesced non-temporal f4 store of the whole tile ----
    {
        const vf4* __restrict__ o4 = (const vf4*)out_lds;
        vf4* __restrict__ g4 = (vf4*)out + (size_t)blockIdx.x * OUT_F4;
        __builtin_nontemporal_store(o4[tid],       &g4[tid]);
        __builtin_nontemporal_store(o4[tid + 256], &g4[tid + 256]);
        if (tid < OUT_F4 - 512)
            __builtin_nontemporal_store(o4[tid + 512], &g4[tid + 512]);
    }
}

extern "C" void kernel_launch(void* const* d_in, const int* in_sizes, int n_in,
                              void* d_out, int out_size, void* d_ws, size_t ws_size,
                              hipStream_t stream)
{
    const float* x = (const float*)d_in[0];
    float* out = (float*)d_out;
    int n_rows = in_sizes[0] / ROW_IN;     // 131072
    int grid = n_rows / R_BLK;             // 8192 blocks
    feat_kernel<<<grid, 256, 0, stream>>>(x, out);
}